// Round 1
// baseline (32.957 us; speedup 1.0000x reference)
//
#include <hip/hip_runtime.h>

// Problem constants (from reference)
#define LIN   4096
#define LOUT  4097          // (L + 2*PAD - KERNEL) + 1
#define NCH   8
#define NBS   16
#define POS_PER_BLK 32
#define PB    129           // ceil(LOUT / POS_PER_BLK)

// ---------------- register statevector gates (fully unrolled) ----------------
// State index bit layout: qubit j <-> bit (8 >> j); q0 is MSB (matches jnp C-order flatten).

template<int BIT>
__device__ __forceinline__ void apply_rx(float sr[16], float si[16], float c, float s) {
#pragma unroll
  for (int k = 0; k < 16; ++k) {
    if ((k & BIT) == 0) {
      const int a = k, b = k | BIT;
      const float ar = sr[a], ai = si[a], br = sr[b], bi = si[b];
      // a' = c*a - i*s*b ; b' = -i*s*a + c*b
      sr[a] = c * ar + s * bi;
      si[a] = c * ai - s * br;
      sr[b] = c * br + s * ai;
      si[b] = c * bi - s * ar;
    }
  }
}

template<int BIT>
__device__ __forceinline__ void apply_ry(float sr[16], float si[16], float c, float s) {
#pragma unroll
  for (int k = 0; k < 16; ++k) {
    if ((k & BIT) == 0) {
      const int a = k, b = k | BIT;
      const float ar = sr[a], ai = si[a], br = sr[b], bi = si[b];
      // a' = c*a - s*b ; b' = s*a + c*b
      sr[a] = c * ar - s * br;
      si[a] = c * ai - s * bi;
      sr[b] = s * ar + c * br;
      si[b] = s * ai + c * bi;
    }
  }
}

template<int CBIT, int TBIT>
__device__ __forceinline__ void apply_cnot(float sr[16], float si[16]) {
#pragma unroll
  for (int k = 0; k < 16; ++k) {
    if ((k & CBIT) != 0 && (k & TBIT) == 0) {
      const int a = k, b = k | TBIT;
      float t;
      t = sr[a]; sr[a] = sr[b]; sr[b] = t;
      t = si[a]; si[a] = si[b]; si[b] = t;
    }
  }
}

__device__ __forceinline__ void basic_layer(float sr[16], float si[16],
                                            const float c[4], const float s[4]) {
  apply_rx<8>(sr, si, c[0], s[0]);   // qubit 0
  apply_rx<4>(sr, si, c[1], s[1]);   // qubit 1
  apply_rx<2>(sr, si, c[2], s[2]);   // qubit 2
  apply_rx<1>(sr, si, c[3], s[3]);   // qubit 3
  apply_cnot<8, 4>(sr, si);          // CNOT(0,1)
  apply_cnot<4, 2>(sr, si);          // CNOT(1,2)
  apply_cnot<2, 1>(sr, si);          // CNOT(2,3)
  apply_cnot<1, 8>(sr, si);          // CNOT(3,0)
}

// ---------------- main kernel: one thread = one (b, ch, pos) circuit ----------------
__global__ __launch_bounds__(256) void quanv_kernel(const float* __restrict__ x,
                                                    const float* __restrict__ weights,
                                                    float* __restrict__ wsM /* [NBS][4] as uint-float bits */) {
  const int tid = threadIdx.x;
  const int blk = blockIdx.x;
  const int b   = blk / PB;
  const int pb  = blk - b * PB;
  const int ch  = tid & 7;
  const int pos = pb * POS_PER_BLK + (tid >> 3);

  // window values (PADDING=1): win[0] = xp[pos] = x[pos-1], win[1] = xp[pos+1] = x[pos]
  const float* row = x + (((size_t)b * NCH + ch) << 12);
  const float w0 = (pos >= 1 && pos <= LIN) ? row[pos - 1] : 0.0f;
  const float w1 = (pos < LIN) ? row[pos] : 0.0f;

  // precompute trig of fixed weights (t/2) and window (t/2)
  float wc[3][4], wsn[3][4];
#pragma unroll
  for (int l = 0; l < 3; ++l) {
#pragma unroll
    for (int q = 0; q < 4; ++q) {
      __sincosf(weights[l * 4 + q] * 0.5f, &wsn[l][q], &wc[l][q]);
    }
  }
  float c0, s0, c1, s1;
  __sincosf(w0 * 0.5f, &s0, &c0);
  __sincosf(w1 * 0.5f, &s1, &c1);

  // |0000>
  float sr[16], si[16];
#pragma unroll
  for (int k = 0; k < 16; ++k) { sr[k] = 0.0f; si[k] = 0.0f; }
  sr[0] = 1.0f;

  basic_layer(sr, si, wc[0], wsn[0]);

  // layer 1: RY(win0) on q0,q2 ; RY(win1) on q1,q3 ; then basic layer
  apply_ry<8>(sr, si, c0, s0);
  apply_ry<4>(sr, si, c1, s1);
  apply_ry<2>(sr, si, c0, s0);
  apply_ry<1>(sr, si, c1, s1);
  basic_layer(sr, si, wc[1], wsn[1]);

  // layer 2
  apply_ry<8>(sr, si, c0, s0);
  apply_ry<4>(sr, si, c1, s1);
  apply_ry<2>(sr, si, c0, s0);
  apply_ry<1>(sr, si, c1, s1);
  basic_layer(sr, si, wc[2], wsn[2]);

  // expectation values <Z_q>
  float ev[4] = {0.0f, 0.0f, 0.0f, 0.0f};
#pragma unroll
  for (int k = 0; k < 16; ++k) {
    const float p = sr[k] * sr[k] + si[k] * si[k];
    ev[0] += (k & 8) ? -p : p;
    ev[1] += (k & 4) ? -p : p;
    ev[2] += (k & 2) ? -p : p;
    ev[3] += (k & 1) ? -p : p;
  }

  // sum over channels: lanes tid = pos_sub*8 + ch -> butterfly within 8-lane groups
#pragma unroll
  for (int m = 1; m < 8; m <<= 1) {
#pragma unroll
    for (int q = 0; q < 4; ++q) ev[q] += __shfl_xor(ev[q], m, 64);
  }

  // leaders: relu, stash per-position values; block max; one atomic per (b,q)
  __shared__ float lmax[4][POS_PER_BLK];
  const int grp = tid >> 3;  // 0..31
  if (ch == 0) {
#pragma unroll
    for (int q = 0; q < 4; ++q) {
      lmax[q][grp] = (pos < LOUT) ? fmaxf(ev[q], 0.0f) : 0.0f;
    }
  }
  __syncthreads();
  if (tid < 4) {
    float m = 0.0f;
#pragma unroll
    for (int g = 0; g < POS_PER_BLK; ++g) m = fmaxf(m, lmax[tid][g]);
    // relu'd values are >= 0: uint ordering == float ordering
    atomicMax((unsigned int*)(wsM + b * 4 + tid), __float_as_uint(m));
  }
}

// ---------------- epilogue: out[b,f] = sum_q M[b,q]*W[q,f] + bias[f] ----------------
__global__ __launch_bounds__(192) void dense_kernel(const float* __restrict__ M,
                                                    const float* __restrict__ dw,
                                                    const float* __restrict__ db,
                                                    float* __restrict__ out) {
  const int t = threadIdx.x;
  if (t < NBS * 10) {
    const int b = t / 10, f = t - b * 10;
    float acc = db[f];
#pragma unroll
    for (int q = 0; q < 4; ++q) acc += M[b * 4 + q] * dw[q * 10 + f];
    out[t] = acc;
  }
}

extern "C" void kernel_launch(void* const* d_in, const int* in_sizes, int n_in,
                              void* d_out, int out_size, void* d_ws, size_t ws_size,
                              hipStream_t stream) {
  const float* x       = (const float*)d_in[0];  // (16, 8, 4096) f32
  const float* weights = (const float*)d_in[1];  // (3, 4) f32
  const float* dw      = (const float*)d_in[2];  // (4, 10) f32
  const float* db      = (const float*)d_in[3];  // (10,) f32
  float* out = (float*)d_out;                    // (16, 10) f32
  float* M   = (float*)d_ws;                     // 64 floats

  hipMemsetAsync(d_ws, 0, NBS * 4 * sizeof(float), stream);
  quanv_kernel<<<NBS * PB, 256, 0, stream>>>(x, weights, M);
  dense_kernel<<<1, 192, 0, stream>>>(M, dw, db, out);
}